// Round 1
// 467.138 us; speedup vs baseline: 1.0262x; 1.0262x over previous
//
#include <hip/hip_runtime.h>

#define NN 262144
#define NG 2048
#define DX 256
#define HID 256
#define BN_EPS 1e-3f

typedef float f32x4 __attribute__((ext_vector_type(4)));
typedef unsigned int u32x2 __attribute__((ext_vector_type(2)));
typedef short bf16x8 __attribute__((ext_vector_type(8)));

__device__ inline unsigned short f2bf(float f) {
  unsigned int u = __float_as_uint(f);
  u += 0x7fffu + ((u >> 16) & 1u);   // RNE (finite inputs)
  return (unsigned short)(u >> 16);
}

#if defined(__has_builtin)
#if __has_builtin(__builtin_amdgcn_cvt_pk_bf16_f32)
#define HAVE_PK_BF16 1
#endif
#endif

__device__ inline unsigned int pk2bf(float a, float b) {
#ifdef HAVE_PK_BF16
  auto t = __builtin_amdgcn_cvt_pk_bf16_f32(a, b);
  unsigned int r;
  __builtin_memcpy(&r, &t, 4);
  return r;
#else
  return (unsigned int)f2bf(a) | ((unsigned int)f2bf(b) << 16);
#endif
}

// ---------------- prep ----------------
// blocks [0,2048)    : bias0''[g][:] = (gf[g]@W0b + b0)*s0 + t0   (1 graph/block)
// blocks [2048,2112) : pack W0a/W1 into frag-ordered bf16 images
// block  2112        : fold BN scale vectors
__global__ __launch_bounds__(256) void prep(
    const float* __restrict__ gf, const float* __restrict__ W0,
    const float* __restrict__ b0, const float* __restrict__ W1,
    const float* __restrict__ g0v, const float* __restrict__ be0,
    const float* __restrict__ m0v, const float* __restrict__ v0v,
    const float* __restrict__ g1v, const float* __restrict__ be1,
    const float* __restrict__ m1v, const float* __restrict__ v1v,
    const float* __restrict__ b1,
    float* __restrict__ s0v, float* __restrict__ s1v, float* __restrict__ u1v,
    float* __restrict__ bias0, unsigned short* __restrict__ wimg0,
    unsigned short* __restrict__ wimg1)
{
  const int tid = threadIdx.x;
  const int bid = blockIdx.x;
  if (bid < NG) {
    __shared__ float lgf[128];
    if (tid < 128) lgf[tid] = gf[bid * 128 + tid];
    __syncthreads();
    float acc = 0.f;
    #pragma unroll 8
    for (int k = 0; k < 128; ++k)
      acc = fmaf(lgf[k], W0[(256 + k) * 256 + tid], acc);
    float s0n = g0v[tid] * rsqrtf(v0v[tid] + BN_EPS);
    float t0n = be0[tid] - m0v[tid] * s0n;
    bias0[bid * 256 + tid] = (acc + b0[tid]) * s0n + t0n;
  } else if (bid < NG + 64) {
    __shared__ float tile[512];   // 32k x 16n
    int job0 = (bid - NG) * 4;
    for (int jj = 0; jj < 4; ++jj) {
      int job = job0 + jj;                    // (layer, cc, nt)
      int layer = job >> 7, rem = job & 127;
      int cc = rem >> 4, nt = rem & 15;
      const float* Wsrc = layer ? W1 : W0;
      unsigned short* img = layer ? wimg1 : wimg0;
      __syncthreads();
      #pragma unroll
      for (int p = 0; p < 2; ++p) {           // coalesced read
        int kl = p * 16 + (tid >> 4), nl = tid & 15;
        tile[kl * 16 + nl] = Wsrc[(cc * 32 + kl) * 256 + nt * 16 + nl];
      }
      __syncthreads();
      #pragma unroll
      for (int p = 0; p < 2; ++p) {           // frag-ordered coalesced write
        int e = p * 256 + tid;
        int ln = e >> 3, j = e & 7;
        int kl = (ln >> 4) * 8 + j, nl = ln & 15;
        img[(cc * 16 + nt) * 512 + e] = f2bf(tile[kl * 16 + nl]);
      }
    }
  } else {
    float s0n = g0v[tid] * rsqrtf(v0v[tid] + BN_EPS);
    s0v[tid] = s0n;
    float s1n = g1v[tid] * rsqrtf(v1v[tid] + BN_EPS);
    s1v[tid] = s1n;
    u1v[tid] = b1[tid] * s1n + be1[tid] - m1v[tid] * s1n;
  }
}

// ---------------- fused MLP ----------------
// v2: row-contiguous x staging. Each wave streams its 24 full rows (1KB each,
// perfectly linear 24KB sweep -> DRAM page friendly, deep MLP from plain
// register loads), converts f32->bf16 ONCE, and ds_writes into a 48KB bf16
// x-image in the SAME swizzled [row][512B] layout layer 1 uses for h1:
//   16B granule g of row r lives at byte r*512 + ((g ^ (r&7))<<4)
// Layer 0 then reads 1 b128 fragment per (cc,mt) exactly like layer 1, with
// one single barrier for all of staging (vs 5 quarter-barriers + vmcnt(0)
// drains in v1, whose 256B-per-1KB-row quarter sweeps throttled DRAM to
// ~1.4 TB/s effective). Both cc loops get +1-deep weight-frag register
// prefetch and setprio(1) around the MFMA cluster.
__global__ __launch_bounds__(256, 3) void fused_mlp(
    const float* __restrict__ x, const int* __restrict__ bidx,
    const unsigned short* __restrict__ wimg0, const unsigned short* __restrict__ wimg1,
    const float* __restrict__ bias0, const float* __restrict__ s0v,
    const float* __restrict__ s1v, const float* __restrict__ u1v,
    const float* __restrict__ w2, float* __restrict__ out, float* __restrict__ norm)
{
  __shared__ __align__(16) unsigned char sX[49152];  // bf16 x-image; later h1
  __shared__ float zscr[384];
  __shared__ float attb[96];
  __shared__ int gb[96];

  const int tid = threadIdx.x;
  const int wave = tid >> 6, lane = tid & 63;
  const int q = lane >> 4, L = lane & 15;
  const int sw7 = L & 7;
  const int mbase = blockIdx.x * 96;

  int gid[6];
  #pragma unroll
  for (int mt = 0; mt < 6; ++mt) {
    int node = mbase + mt * 16 + L;
    gid[mt] = bidx[(node < NN) ? node : 0];
  }

  // ---- stage x rows (bf16) into sX; one full 1KB row per instruction ----
  {
    const int r0 = wave * 24;
    #pragma unroll
    for (int r = 0; r < 24; ++r) {
      int row = r0 + r;
      int node = mbase + row;
      node = (node < NN) ? node : (NN - 1);
      f32x4 v = *(const f32x4*)(x + (long)node * 256 + lane * 4);
      u32x2 pk;
      pk.x = pk2bf(v.x, v.y);
      pk.y = pk2bf(v.z, v.w);
      // floats lane*4.. -> bf16 16B-granule g=lane>>1, half lane&1; swizzled
      *(u32x2*)(sX + row * 512 + ((((lane >> 1) ^ (row & 7))) << 4) + (lane & 1) * 8) = pk;
    }
  }

  f32x4 acc[4][6];
  #pragma unroll
  for (int t = 0; t < 4; ++t)
    #pragma unroll
    for (int mt = 0; mt < 6; ++mt) acc[t][mt] = (f32x4)0.0f;

  // preload layer-0 cc=0 weight frags (global; overlaps the barrier wait)
  const unsigned short* w0p = wimg0 + ((wave * 4) << 9) + lane * 8;
  bf16x8 wf0 = *(const bf16x8*)(w0p);
  bf16x8 wf1 = *(const bf16x8*)(w0p + 512);
  bf16x8 wf2 = *(const bf16x8*)(w0p + 1024);
  bf16x8 wf3 = *(const bf16x8*)(w0p + 1536);

  __syncthreads();                                   // x-image complete

  // ---- layer 0: 8 K-tiles, frags from LDS, weights double-buffered ----
  #pragma unroll 1
  for (int cc = 0; cc < 8; ++cc) {
    const unsigned short* np = w0p + ((((cc + 1) & 7) * 16) << 9);
    bf16x8 nf0 = *(const bf16x8*)(np);
    bf16x8 nf1 = *(const bf16x8*)(np + 512);
    bf16x8 nf2 = *(const bf16x8*)(np + 1024);
    bf16x8 nf3 = *(const bf16x8*)(np + 1536);
    const int gxb = ((cc * 4 + q) ^ sw7) << 4;
    __builtin_amdgcn_s_setprio(1);
    #pragma unroll
    for (int mt = 0; mt < 6; ++mt) {
      bf16x8 xf = *(const bf16x8*)(sX + (mt * 16 + L) * 512 + gxb);
      acc[0][mt] = __builtin_amdgcn_mfma_f32_16x16x32_bf16(wf0, xf, acc[0][mt], 0, 0, 0);
      acc[1][mt] = __builtin_amdgcn_mfma_f32_16x16x32_bf16(wf1, xf, acc[1][mt], 0, 0, 0);
      acc[2][mt] = __builtin_amdgcn_mfma_f32_16x16x32_bf16(wf2, xf, acc[2][mt], 0, 0, 0);
      acc[3][mt] = __builtin_amdgcn_mfma_f32_16x16x32_bf16(wf3, xf, acc[3][mt], 0, 0, 0);
    }
    __builtin_amdgcn_s_setprio(0);
    wf0 = nf0; wf1 = nf1; wf2 = nf2; wf3 = nf3;
  }
  __syncthreads();                                   // all x reads done; sX reusable

  // ---- epilogue 0: h1 = relu(acc*s0 + bias0''[g]) -> bf16 -> sX as h1 ----
  #pragma unroll
  for (int t = 0; t < 4; ++t) {
    int n0 = (wave * 4 + t) * 16 + q * 4;
    f32x4 s0q = *(const f32x4*)(s0v + n0);
    int gwb = ((n0 >> 3) ^ sw7) << 4;
    int boff = (q & 1) << 3;
    #pragma unroll
    for (int mt = 0; mt < 6; ++mt) {
      f32x4 bq = *(const f32x4*)(bias0 + gid[mt] * HID + n0);
      float h0 = fmaxf(fmaf(acc[t][mt].x, s0q.x, bq.x), 0.f);
      float h1 = fmaxf(fmaf(acc[t][mt].y, s0q.y, bq.y), 0.f);
      float h2 = fmaxf(fmaf(acc[t][mt].z, s0q.z, bq.z), 0.f);
      float h3 = fmaxf(fmaf(acc[t][mt].w, s0q.w, bq.w), 0.f);
      u32x2 pk;
      pk.x = pk2bf(h0, h1);
      pk.y = pk2bf(h2, h3);
      *(u32x2*)(sX + (mt * 16 + L) * 512 + gwb + boff) = pk;
      acc[t][mt] = (f32x4)0.0f;
    }
  }

  // preload layer-1 cc=0 weight frags (overlaps the barrier wait)
  const unsigned short* w1p = wimg1 + ((wave * 4) << 9) + lane * 8;
  bf16x8 vf0 = *(const bf16x8*)(w1p);
  bf16x8 vf1 = *(const bf16x8*)(w1p + 512);
  bf16x8 vf2 = *(const bf16x8*)(w1p + 1024);
  bf16x8 vf3 = *(const bf16x8*)(w1p + 1536);

  __syncthreads();                                   // h1 complete

  // ---- layer 1: h1 frags from LDS (swizzled), weights double-buffered ----
  #pragma unroll 1
  for (int cc = 0; cc < 8; ++cc) {
    const unsigned short* np = w1p + ((((cc + 1) & 7) * 16) << 9);
    bf16x8 nf0 = *(const bf16x8*)(np);
    bf16x8 nf1 = *(const bf16x8*)(np + 512);
    bf16x8 nf2 = *(const bf16x8*)(np + 1024);
    bf16x8 nf3 = *(const bf16x8*)(np + 1536);
    const int g1b = ((cc * 4 + q) ^ sw7) << 4;
    __builtin_amdgcn_s_setprio(1);
    #pragma unroll
    for (int mt = 0; mt < 6; ++mt) {
      bf16x8 hf = *(const bf16x8*)(sX + (mt * 16 + L) * 512 + g1b);
      acc[0][mt] = __builtin_amdgcn_mfma_f32_16x16x32_bf16(vf0, hf, acc[0][mt], 0, 0, 0);
      acc[1][mt] = __builtin_amdgcn_mfma_f32_16x16x32_bf16(vf1, hf, acc[1][mt], 0, 0, 0);
      acc[2][mt] = __builtin_amdgcn_mfma_f32_16x16x32_bf16(vf2, hf, acc[2][mt], 0, 0, 0);
      acc[3][mt] = __builtin_amdgcn_mfma_f32_16x16x32_bf16(vf3, hf, acc[3][mt], 0, 0, 0);
    }
    __builtin_amdgcn_s_setprio(0);
    vf0 = nf0; vf1 = nf1; vf2 = nf2; vf3 = nf3;
  }

  // ---- epilogue 1 + layer 2 (fp32): z = sum_n relu(acc*s1+u1)*w2 ----
  float zp[6] = {0.f, 0.f, 0.f, 0.f, 0.f, 0.f};
  #pragma unroll
  for (int t = 0; t < 4; ++t) {
    int n0 = (wave * 4 + t) * 16 + q * 4;
    f32x4 s1q = *(const f32x4*)(s1v + n0);
    f32x4 u1q = *(const f32x4*)(u1v + n0);
    f32x4 w2q = *(const f32x4*)(w2 + n0);
    #pragma unroll
    for (int mt = 0; mt < 6; ++mt) {
      float h0 = fmaxf(fmaf(acc[t][mt].x, s1q.x, u1q.x), 0.f);
      float h1 = fmaxf(fmaf(acc[t][mt].y, s1q.y, u1q.y), 0.f);
      float h2 = fmaxf(fmaf(acc[t][mt].z, s1q.z, u1q.z), 0.f);
      float h3 = fmaxf(fmaf(acc[t][mt].w, s1q.w, u1q.w), 0.f);
      zp[mt] += h0 * w2q.x + h1 * w2q.y + h2 * w2q.z + h3 * w2q.w;
    }
  }
  #pragma unroll
  for (int mt = 0; mt < 6; ++mt) {
    float z = zp[mt];
    z += __shfl_xor(z, 16, 64);
    z += __shfl_xor(z, 32, 64);
    zp[mt] = z;
  }
  if (q == 0) {
    #pragma unroll
    for (int mt = 0; mt < 6; ++mt) zscr[wave * 96 + mt * 16 + L] = zp[mt];
  }
  __syncthreads();
  if (tid < 96) {
    int node = mbase + tid;
    float z = zscr[tid] + zscr[96 + tid] + zscr[192 + tid] + zscr[288 + tid];
    float a = __expf(z);
    bool v = node < NN;
    if (v) out[node] = a;
    attb[tid] = v ? a : 0.f;
    gb[tid] = v ? bidx[node] : -1;
  }
  __syncthreads();
  if (tid < 96) {
    int g = gb[tid];
    if (g >= 0 && (tid == 0 || gb[tid - 1] != g)) {   // segment head
      float s = attb[tid];
      for (int i = tid + 1; i < 96 && gb[i] == g; ++i) s += attb[i];
      atomicAdd(&norm[g], s);
    }
  }
}

// ---------------- normalize ----------------
__global__ __launch_bounds__(256) void norm_div(float* __restrict__ out,
                                                const int* __restrict__ bidx,
                                                const float* __restrict__ norm) {
  int i = blockIdx.x * 256 + threadIdx.x;
  out[i] = out[i] / norm[bidx[i]];
}

extern "C" void kernel_launch(void* const* d_in, const int* in_sizes, int n_in,
                              void* d_out, int out_size, void* d_ws, size_t ws_size,
                              hipStream_t stream) {
  const float* x   = (const float*)d_in[0];
  const int*   bidx= (const int*)d_in[1];
  const float* gf  = (const float*)d_in[2];
  const float* W0  = (const float*)d_in[3];
  const float* b0  = (const float*)d_in[4];
  const float* W1  = (const float*)d_in[5];
  const float* b1  = (const float*)d_in[6];
  const float* W2  = (const float*)d_in[7];
  // d_in[8] = b2: cancels in att/normalizer ratio
  const float* g0v = (const float*)d_in[9];
  const float* be0 = (const float*)d_in[10];
  const float* m0v = (const float*)d_in[11];
  const float* v0v = (const float*)d_in[12];
  const float* g1v = (const float*)d_in[13];
  const float* be1 = (const float*)d_in[14];
  const float* m1v = (const float*)d_in[15];
  const float* v1v = (const float*)d_in[16];

  float* ws    = (float*)d_ws;
  float* norm  = ws;                 // 2048 f32
  float* s0v   = ws + 2048;          // 256
  float* s1v   = ws + 2304;          // 256
  float* u1v   = ws + 2560;          // 256
  float* bias0 = ws + 4096;          // 2048*256 f32 = 2 MB
  unsigned short* wimg0 = (unsigned short*)(ws + 4096 + 524288);  // 128 KB bf16
  unsigned short* wimg1 = wimg0 + 65536;                          // 128 KB bf16

  hipMemsetAsync(norm, 0, 2048 * sizeof(float), stream);
  prep<<<NG + 65, 256, 0, stream>>>(gf, W0, b0, W1, g0v, be0, m0v, v0v,
                                    g1v, be1, m1v, v1v, b1,
                                    s0v, s1v, u1v, bias0, wimg0, wimg1);
  fused_mlp<<<2731, 256, 0, stream>>>(x, bidx, wimg0, wimg1, bias0,
                                      s0v, s1v, u1v, W2, (float*)d_out, norm);
  norm_div<<<1024, 256, 0, stream>>>((float*)d_out, bidx, norm);
}

// Round 2
// 446.876 us; speedup vs baseline: 1.0727x; 1.0453x over previous
//
#include <hip/hip_runtime.h>

#define NN 262144
#define NG 2048
#define DX 256
#define HID 256
#define BN_EPS 1e-3f

typedef float f32x4 __attribute__((ext_vector_type(4)));
typedef unsigned int u32x2 __attribute__((ext_vector_type(2)));
typedef short bf16x8 __attribute__((ext_vector_type(8)));

__device__ inline unsigned short f2bf(float f) {
  unsigned int u = __float_as_uint(f);
  u += 0x7fffu + ((u >> 16) & 1u);   // RNE (finite inputs)
  return (unsigned short)(u >> 16);
}

#if defined(__has_builtin)
#if __has_builtin(__builtin_amdgcn_cvt_pk_bf16_f32)
#define HAVE_PK_BF16 1
#endif
#endif

__device__ inline unsigned int pk2bf(float a, float b) {
#ifdef HAVE_PK_BF16
  auto t = __builtin_amdgcn_cvt_pk_bf16_f32(a, b);
  unsigned int r;
  __builtin_memcpy(&r, &t, 4);
  return r;
#else
  return (unsigned int)f2bf(a) | ((unsigned int)f2bf(b) << 16);
#endif
}

// ---------------- prep ----------------
// blocks [0,512)   : bias0''[g][:] for 4 graphs/block (W0-slab load reused 4x)
// blocks [512,576) : pack W0a/W1 into frag-ordered bf16 images
// block  576       : fold BN scale vectors
__global__ __launch_bounds__(256) void prep(
    const float* __restrict__ gf, const float* __restrict__ W0,
    const float* __restrict__ b0, const float* __restrict__ W1,
    const float* __restrict__ g0v, const float* __restrict__ be0,
    const float* __restrict__ m0v, const float* __restrict__ v0v,
    const float* __restrict__ g1v, const float* __restrict__ be1,
    const float* __restrict__ m1v, const float* __restrict__ v1v,
    const float* __restrict__ b1,
    float* __restrict__ s0v, float* __restrict__ s1v, float* __restrict__ u1v,
    float* __restrict__ bias0, unsigned short* __restrict__ wimg0,
    unsigned short* __restrict__ wimg1)
{
  const int tid = threadIdx.x;
  const int bid = blockIdx.x;
  if (bid < 512) {
    __shared__ float lgf[512];            // 4 graphs x 128
    lgf[tid] = gf[bid * 512 + tid];
    lgf[256 + tid] = gf[bid * 512 + 256 + tid];
    __syncthreads();
    float a0 = 0.f, a1 = 0.f, a2 = 0.f, a3 = 0.f;
    #pragma unroll 8
    for (int k = 0; k < 128; ++k) {
      float w = W0[(256 + k) * 256 + tid];
      a0 = fmaf(lgf[k], w, a0);
      a1 = fmaf(lgf[128 + k], w, a1);
      a2 = fmaf(lgf[256 + k], w, a2);
      a3 = fmaf(lgf[384 + k], w, a3);
    }
    float s0n = g0v[tid] * rsqrtf(v0v[tid] + BN_EPS);
    float bb = b0[tid];
    float t0n = be0[tid] - m0v[tid] * s0n;
    bias0[(bid * 4 + 0) * 256 + tid] = (a0 + bb) * s0n + t0n;
    bias0[(bid * 4 + 1) * 256 + tid] = (a1 + bb) * s0n + t0n;
    bias0[(bid * 4 + 2) * 256 + tid] = (a2 + bb) * s0n + t0n;
    bias0[(bid * 4 + 3) * 256 + tid] = (a3 + bb) * s0n + t0n;
  } else if (bid < 512 + 64) {
    __shared__ float tile[512];   // 32k x 16n
    int job0 = (bid - 512) * 4;
    for (int jj = 0; jj < 4; ++jj) {
      int job = job0 + jj;                    // (layer, cc, nt)
      int layer = job >> 7, rem = job & 127;
      int cc = rem >> 4, nt = rem & 15;
      const float* Wsrc = layer ? W1 : W0;
      unsigned short* img = layer ? wimg1 : wimg0;
      __syncthreads();
      #pragma unroll
      for (int p = 0; p < 2; ++p) {           // coalesced read
        int kl = p * 16 + (tid >> 4), nl = tid & 15;
        tile[kl * 16 + nl] = Wsrc[(cc * 32 + kl) * 256 + nt * 16 + nl];
      }
      __syncthreads();
      #pragma unroll
      for (int p = 0; p < 2; ++p) {           // frag-ordered coalesced write
        int e = p * 256 + tid;
        int ln = e >> 3, j = e & 7;
        int kl = (ln >> 4) * 8 + j, nl = ln & 15;
        img[(cc * 16 + nt) * 512 + e] = f2bf(tile[kl * 16 + nl]);
      }
    }
  } else {
    float s0n = g0v[tid] * rsqrtf(v0v[tid] + BN_EPS);
    s0v[tid] = s0n;
    float s1n = g1v[tid] * rsqrtf(v1v[tid] + BN_EPS);
    s1v[tid] = s1n;
    u1v[tid] = b1[tid] * s1n + be1[tid] - m1v[tid] * s1n;
  }
}

// ---------------- fused MLP ----------------
// v3: M=64 tile (4096 blocks, exact divide of NN -> zero bounds clamps).
// Register cliff fixed: acc[4][4] (64 regs) + 8 weight frags (32) + addressing
// keeps combined VGPR+AGPR <= 128 -> 4 waves/SIMD; sX shrinks to 32KB ->
// 4 blocks/CU. 16 waves/CU (50% occ) vs v2's 8 (26%, reg-capped at 176).
// Staging: each wave holds all 16 of its x rows in flight (64 VGPRs, dead
// after staging) -> 256KB in flight per CU, fully covering HBM latency.
__global__ __launch_bounds__(256, 4) void fused_mlp(
    const float* __restrict__ x, const int* __restrict__ bidx,
    const unsigned short* __restrict__ wimg0, const unsigned short* __restrict__ wimg1,
    const float* __restrict__ bias0, const float* __restrict__ s0v,
    const float* __restrict__ s1v, const float* __restrict__ u1v,
    const float* __restrict__ w2, float* __restrict__ out, float* __restrict__ norm)
{
  __shared__ __align__(16) unsigned char sX[32768];  // bf16 x-image; later h1
  __shared__ float zscr[256];
  __shared__ float attb[64];
  __shared__ int gb[64];

  const int tid = threadIdx.x;
  const int wave = tid >> 6, lane = tid & 63;
  const int q = lane >> 4, L = lane & 15;
  const int sw7 = L & 7;
  const int mbase = blockIdx.x * 64;

  int gid[4];
  #pragma unroll
  for (int mt = 0; mt < 4; ++mt)
    gid[mt] = bidx[mbase + mt * 16 + L];

  // ---- stage 16 x rows per wave (all loads in flight), cvt bf16 -> sX ----
  {
    const int r0 = wave * 16;
    f32x4 xr[16];
    #pragma unroll
    for (int r = 0; r < 16; ++r)
      xr[r] = *(const f32x4*)(x + (long)(mbase + r0 + r) * 256 + lane * 4);
    #pragma unroll
    for (int r = 0; r < 16; ++r) {
      int row = r0 + r;
      u32x2 pk;
      pk.x = pk2bf(xr[r].x, xr[r].y);
      pk.y = pk2bf(xr[r].z, xr[r].w);
      // floats lane*4.. -> bf16 16B-granule g=lane>>1, half lane&1; swizzled
      *(u32x2*)(sX + row * 512 + ((((lane >> 1) ^ (row & 7))) << 4) + (lane & 1) * 8) = pk;
    }
  }

  f32x4 acc[4][4];
  #pragma unroll
  for (int t = 0; t < 4; ++t)
    #pragma unroll
    for (int mt = 0; mt < 4; ++mt) acc[t][mt] = (f32x4)0.0f;

  // preload layer-0 cc=0 weight frags (global; overlaps the barrier wait)
  const unsigned short* w0p = wimg0 + ((wave * 4) << 9) + lane * 8;
  bf16x8 wf0 = *(const bf16x8*)(w0p);
  bf16x8 wf1 = *(const bf16x8*)(w0p + 512);
  bf16x8 wf2 = *(const bf16x8*)(w0p + 1024);
  bf16x8 wf3 = *(const bf16x8*)(w0p + 1536);

  __syncthreads();                                   // x-image complete

  // ---- layer 0: 8 K-tiles, frags from LDS, weights double-buffered ----
  #pragma unroll 1
  for (int cc = 0; cc < 8; ++cc) {
    const unsigned short* np = w0p + ((((cc + 1) & 7) * 16) << 9);
    bf16x8 nf0 = *(const bf16x8*)(np);
    bf16x8 nf1 = *(const bf16x8*)(np + 512);
    bf16x8 nf2 = *(const bf16x8*)(np + 1024);
    bf16x8 nf3 = *(const bf16x8*)(np + 1536);
    const int gxb = ((cc * 4 + q) ^ sw7) << 4;
    __builtin_amdgcn_s_setprio(1);
    #pragma unroll
    for (int mt = 0; mt < 4; ++mt) {
      bf16x8 xf = *(const bf16x8*)(sX + (mt * 16 + L) * 512 + gxb);
      acc[0][mt] = __builtin_amdgcn_mfma_f32_16x16x32_bf16(wf0, xf, acc[0][mt], 0, 0, 0);
      acc[1][mt] = __builtin_amdgcn_mfma_f32_16x16x32_bf16(wf1, xf, acc[1][mt], 0, 0, 0);
      acc[2][mt] = __builtin_amdgcn_mfma_f32_16x16x32_bf16(wf2, xf, acc[2][mt], 0, 0, 0);
      acc[3][mt] = __builtin_amdgcn_mfma_f32_16x16x32_bf16(wf3, xf, acc[3][mt], 0, 0, 0);
    }
    __builtin_amdgcn_s_setprio(0);
    wf0 = nf0; wf1 = nf1; wf2 = nf2; wf3 = nf3;
  }
  __syncthreads();                                   // all x reads done; sX reusable

  // ---- epilogue 0: h1 = relu(acc*s0 + bias0''[g]) -> bf16 -> sX as h1 ----
  #pragma unroll
  for (int t = 0; t < 4; ++t) {
    int n0 = (wave * 4 + t) * 16 + q * 4;
    f32x4 s0q = *(const f32x4*)(s0v + n0);
    int gwb = ((n0 >> 3) ^ sw7) << 4;
    int boff = (q & 1) << 3;
    #pragma unroll
    for (int mt = 0; mt < 4; ++mt) {
      f32x4 bq = *(const f32x4*)(bias0 + gid[mt] * HID + n0);
      float h0 = fmaxf(fmaf(acc[t][mt].x, s0q.x, bq.x), 0.f);
      float h1 = fmaxf(fmaf(acc[t][mt].y, s0q.y, bq.y), 0.f);
      float h2 = fmaxf(fmaf(acc[t][mt].z, s0q.z, bq.z), 0.f);
      float h3 = fmaxf(fmaf(acc[t][mt].w, s0q.w, bq.w), 0.f);
      u32x2 pk;
      pk.x = pk2bf(h0, h1);
      pk.y = pk2bf(h2, h3);
      *(u32x2*)(sX + (mt * 16 + L) * 512 + gwb + boff) = pk;
      acc[t][mt] = (f32x4)0.0f;
    }
  }

  // preload layer-1 cc=0 weight frags (overlaps the barrier wait)
  const unsigned short* w1p = wimg1 + ((wave * 4) << 9) + lane * 8;
  bf16x8 vf0 = *(const bf16x8*)(w1p);
  bf16x8 vf1 = *(const bf16x8*)(w1p + 512);
  bf16x8 vf2 = *(const bf16x8*)(w1p + 1024);
  bf16x8 vf3 = *(const bf16x8*)(w1p + 1536);

  __syncthreads();                                   // h1 complete

  // ---- layer 1: h1 frags from LDS (swizzled), weights double-buffered ----
  #pragma unroll 1
  for (int cc = 0; cc < 8; ++cc) {
    const unsigned short* np = w1p + ((((cc + 1) & 7) * 16) << 9);
    bf16x8 nf0 = *(const bf16x8*)(np);
    bf16x8 nf1 = *(const bf16x8*)(np + 512);
    bf16x8 nf2 = *(const bf16x8*)(np + 1024);
    bf16x8 nf3 = *(const bf16x8*)(np + 1536);
    const int g1b = ((cc * 4 + q) ^ sw7) << 4;
    __builtin_amdgcn_s_setprio(1);
    #pragma unroll
    for (int mt = 0; mt < 4; ++mt) {
      bf16x8 hf = *(const bf16x8*)(sX + (mt * 16 + L) * 512 + g1b);
      acc[0][mt] = __builtin_amdgcn_mfma_f32_16x16x32_bf16(vf0, hf, acc[0][mt], 0, 0, 0);
      acc[1][mt] = __builtin_amdgcn_mfma_f32_16x16x32_bf16(vf1, hf, acc[1][mt], 0, 0, 0);
      acc[2][mt] = __builtin_amdgcn_mfma_f32_16x16x32_bf16(vf2, hf, acc[2][mt], 0, 0, 0);
      acc[3][mt] = __builtin_amdgcn_mfma_f32_16x16x32_bf16(vf3, hf, acc[3][mt], 0, 0, 0);
    }
    __builtin_amdgcn_s_setprio(0);
    vf0 = nf0; vf1 = nf1; vf2 = nf2; vf3 = nf3;
  }

  // ---- epilogue 1 + layer 2 (fp32): z = sum_n relu(acc*s1+u1)*w2 ----
  float zp[4] = {0.f, 0.f, 0.f, 0.f};
  #pragma unroll
  for (int t = 0; t < 4; ++t) {
    int n0 = (wave * 4 + t) * 16 + q * 4;
    f32x4 s1q = *(const f32x4*)(s1v + n0);
    f32x4 u1q = *(const f32x4*)(u1v + n0);
    f32x4 w2q = *(const f32x4*)(w2 + n0);
    #pragma unroll
    for (int mt = 0; mt < 4; ++mt) {
      float h0 = fmaxf(fmaf(acc[t][mt].x, s1q.x, u1q.x), 0.f);
      float h1 = fmaxf(fmaf(acc[t][mt].y, s1q.y, u1q.y), 0.f);
      float h2 = fmaxf(fmaf(acc[t][mt].z, s1q.z, u1q.z), 0.f);
      float h3 = fmaxf(fmaf(acc[t][mt].w, s1q.w, u1q.w), 0.f);
      zp[mt] += h0 * w2q.x + h1 * w2q.y + h2 * w2q.z + h3 * w2q.w;
    }
  }
  #pragma unroll
  for (int mt = 0; mt < 4; ++mt) {
    float z = zp[mt];
    z += __shfl_xor(z, 16, 64);
    z += __shfl_xor(z, 32, 64);
    zp[mt] = z;
  }
  if (q == 0) {
    #pragma unroll
    for (int mt = 0; mt < 4; ++mt) zscr[wave * 64 + mt * 16 + L] = zp[mt];
  }
  __syncthreads();
  if (tid < 64) {
    int node = mbase + tid;
    float z = zscr[tid] + zscr[64 + tid] + zscr[128 + tid] + zscr[192 + tid];
    float a = __expf(z);
    out[node] = a;
    attb[tid] = a;
    gb[tid] = bidx[node];
  }
  __syncthreads();
  if (tid < 64) {
    int g = gb[tid];
    if (tid == 0 || gb[tid - 1] != g) {               // segment head
      float s = attb[tid];
      for (int i = tid + 1; i < 64 && gb[i] == g; ++i) s += attb[i];
      atomicAdd(&norm[g], s);
    }
  }
}

// ---------------- normalize ----------------
__global__ __launch_bounds__(256) void norm_div(float* __restrict__ out,
                                                const int* __restrict__ bidx,
                                                const float* __restrict__ norm) {
  int i = blockIdx.x * 256 + threadIdx.x;
  out[i] = out[i] / norm[bidx[i]];
}

extern "C" void kernel_launch(void* const* d_in, const int* in_sizes, int n_in,
                              void* d_out, int out_size, void* d_ws, size_t ws_size,
                              hipStream_t stream) {
  const float* x   = (const float*)d_in[0];
  const int*   bidx= (const int*)d_in[1];
  const float* gf  = (const float*)d_in[2];
  const float* W0  = (const float*)d_in[3];
  const float* b0  = (const float*)d_in[4];
  const float* W1  = (const float*)d_in[5];
  const float* b1  = (const float*)d_in[6];
  const float* W2  = (const float*)d_in[7];
  // d_in[8] = b2: cancels in att/normalizer ratio
  const float* g0v = (const float*)d_in[9];
  const float* be0 = (const float*)d_in[10];
  const float* m0v = (const float*)d_in[11];
  const float* v0v = (const float*)d_in[12];
  const float* g1v = (const float*)d_in[13];
  const float* be1 = (const float*)d_in[14];
  const float* m1v = (const float*)d_in[15];
  const float* v1v = (const float*)d_in[16];

  float* ws    = (float*)d_ws;
  float* norm  = ws;                 // 2048 f32
  float* s0v   = ws + 2048;          // 256
  float* s1v   = ws + 2304;          // 256
  float* u1v   = ws + 2560;          // 256
  float* bias0 = ws + 4096;          // 2048*256 f32 = 2 MB
  unsigned short* wimg0 = (unsigned short*)(ws + 4096 + 524288);  // 128 KB bf16
  unsigned short* wimg1 = wimg0 + 65536;                          // 128 KB bf16

  hipMemsetAsync(norm, 0, 2048 * sizeof(float), stream);
  prep<<<512 + 65, 256, 0, stream>>>(gf, W0, b0, W1, g0v, be0, m0v, v0v,
                                     g1v, be1, m1v, v1v, b1,
                                     s0v, s1v, u1v, bias0, wimg0, wimg1);
  fused_mlp<<<4096, 256, 0, stream>>>(x, bidx, wimg0, wimg1, bias0,
                                      s0v, s1v, u1v, W2, (float*)d_out, norm);
  norm_div<<<1024, 256, 0, stream>>>((float*)d_out, bidx, norm);
}